// Round 8
// baseline (412.332 us; speedup 1.0000x reference)
//
#include <hip/hip_runtime.h>

#define NBINS   20
#define NSETS   32          // replicated global accumulator slots (power of 2)
#define BLOCKS  2048
#define TPB     256
#define PACK    256.0f      // A = 256*cnt + sse ; per-thread cnt<=32, sse<32 -> exact decode

// Per-tile compute: 4 elements -> packed (cnt,sse) routed into 20 register bins.
// All acc indexing is compile-time (full unroll) -> stays in VGPRs (no scratch).
__device__ __forceinline__ void body(const float4 p, const float4 t, float (&acc)[NBINS])
{
    float d0 = p.x - t.x; float a0 = fmaf(d0, d0, PACK);
    float d1 = p.y - t.y; float a1 = fmaf(d1, d1, PACK);
    float d2 = p.z - t.z; float a2 = fmaf(d2, d2, PACK);
    float d3 = p.w - t.w; float a3 = fmaf(d3, d3, PACK);
    int b0 = min(max((int)(t.x * 20.0f), 0), NBINS - 1);
    int b1 = min(max((int)(t.y * 20.0f), 0), NBINS - 1);
    int b2 = min(max((int)(t.z * 20.0f), 0), NBINS - 1);
    int b3 = min(max((int)(t.w * 20.0f), 0), NBINS - 1);
    #pragma unroll
    for (int bb = 0; bb < NBINS; ++bb) {
        float add = ((bb == b0) ? a0 : 0.0f) + ((bb == b1) ? a1 : 0.0f)
                  + ((bb == b2) ? a2 : 0.0f) + ((bb == b3) ? a3 : 0.0f);
        acc[bb] += add;
    }
}

// ---------------- Fused single-pass kernel ----------------
// r2 win: register-resident bin accumulators.
// r7: (A) specialized iters==8 path at BLOCKS=2048: ALL 16 dwordx4 loads issue
//     up-front in one basic block (16 KB in flight/wave, ~92 live VGPRs under
//     the (TPB,4)=128 cap) -> clean within-wave memory/VALU overlap test.
//     (B) pass2 fused via last-block-done: saves one dispatch (~100 us of the
//     158 us total is outside pass1; 3 dispatches -> 2).
__global__ __launch_bounds__(TPB, 4)
void dwmse_pass1(const float* __restrict__ pred, const float* __restrict__ targ,
                 float* __restrict__ ws, float* __restrict__ out,
                 int n, int setMask, int nsets, float inv_n)
{
    __shared__ float h[NBINS * TPB];     // 20 KB -> LDS caps 8 blocks/CU
    __shared__ int   isLast;
    const int tid = threadIdx.x;

    float acc[NBINS];
    #pragma unroll
    for (int b = 0; b < NBINS; ++b) acc[b] = 0.0f;

    const int n4 = n >> 2;
    const float4* p4 = reinterpret_cast<const float4*>(pred);
    const float4* t4 = reinterpret_cast<const float4*>(targ);
    const int idx0    = blockIdx.x * TPB + tid;
    const int gstride = gridDim.x * TPB;

    const int iters = n4 / gstride;          // 8 @ N=2^24, BLOCKS=2048
    const int rem   = n4 - iters * gstride;

    if (iters == 8 && rem == 0) {
        // ---- hot path: issue ALL loads, then compute (single basic block) ----
        const float4* pp = p4 + idx0;
        const float4* tt = t4 + idx0;
        float4 T0 = tt[0];           float4 P0 = pp[0];
        float4 T1 = tt[gstride];     float4 P1 = pp[gstride];
        float4 T2 = tt[2 * gstride]; float4 P2 = pp[2 * gstride];
        float4 T3 = tt[3 * gstride]; float4 P3 = pp[3 * gstride];
        float4 T4 = tt[4 * gstride]; float4 P4 = pp[4 * gstride];
        float4 T5 = tt[5 * gstride]; float4 P5 = pp[5 * gstride];
        float4 T6 = tt[6 * gstride]; float4 P6 = pp[6 * gstride];
        float4 T7 = tt[7 * gstride]; float4 P7 = pp[7 * gstride];
        body(P0, T0, acc); body(P1, T1, acc);
        body(P2, T2, acc); body(P3, T3, acc);
        body(P4, T4, acc); body(P5, T5, acc);
        body(P6, T6, acc); body(P7, T7, acc);
    } else {
        // ---- generic fallback (any n): branch-free counted pipeline ----
        if (iters >= 2) {
            const float4* pp = p4 + idx0;
            const float4* tt = t4 + idx0;
            float4 pa = pp[0];       float4 ta = tt[0];
            float4 pb = pp[gstride]; float4 tb = tt[gstride];
            for (int it = 0; it < iters - 2; ++it) {
                float4 pc = pp[2 * gstride];
                float4 tc = tt[2 * gstride];
                pp += gstride; tt += gstride;
                body(pa, ta, acc);
                pa = pb; ta = tb;
                pb = pc; tb = tc;
            }
            body(pa, ta, acc);
            body(pb, tb, acc);
        } else if (iters == 1) {
            body(p4[idx0], t4[idx0], acc);
        }
        if (idx0 < rem) {
            body(p4[iters * gstride + idx0], t4[iters * gstride + idx0], acc);
        }
        for (int k = (n4 << 2) + idx0; k < n; k += gstride) {
            float t = targ[k];
            float d = pred[k] - t; float a = fmaf(d, d, PACK);
            int b = min(max((int)(t * 20.0f), 0), NBINS - 1);
            #pragma unroll
            for (int bb = 0; bb < NBINS; ++bb) acc[bb] += (bb == b) ? a : 0.0f;
        }
    }

    // ---- decode per thread (exact: cnt<=32, sse<32), stage sse in LDS ----
    #pragma unroll
    for (int b = 0; b < NBINS; ++b) {
        float A = acc[b];
        float c = floorf(A * (1.0f / 256.0f));
        float s = A - 256.0f * c;
        h[b * TPB + tid] = s;            // phase A payload
        acc[b] = c;                      // keep counts for phase B
    }
    __syncthreads();

    // ---- phase A: 160 readers, each sums 32 consecutive (staggered) slots ----
    const int rbin = tid >> 3;           // bin for readers (tid < 160)
    const int rchk = tid & 7;            // chunk within bin
    float pA = 0.0f;
    if (tid < NBINS * 8) {
        const int base = rbin * TPB + rchk * 32;
        #pragma unroll
        for (int k = 0; k < 32; ++k)
            pA += h[base + ((k + tid) & 31)];   // stagger -> conflict-free
    }
    pA += __shfl_down(pA, 4);            // combine 8 chunks (aligned groups)
    pA += __shfl_down(pA, 2);
    pA += __shfl_down(pA, 1);
    const float blk_sse = pA;            // valid at rchk==0

    __syncthreads();                     // phase A reads done -> reuse h
    #pragma unroll
    for (int b = 0; b < NBINS; ++b) h[b * TPB + tid] = acc[b];
    __syncthreads();

    float pB = 0.0f;
    if (tid < NBINS * 8) {
        const int base = rbin * TPB + rchk * 32;
        #pragma unroll
        for (int k = 0; k < 32; ++k)
            pB += h[base + ((k + tid) & 31)];
    }
    pB += __shfl_down(pB, 4);
    pB += __shfl_down(pB, 2);
    pB += __shfl_down(pB, 1);

    if (tid < NBINS * 8 && rchk == 0) {
        const int set = (int)(blockIdx.x) & setMask;
        unsafeAtomicAdd(&ws[set * 2 * NBINS + rbin], blk_sse);
        unsafeAtomicAdd(&ws[set * 2 * NBINS + NBINS + rbin], pB);
    }

    // ---- fused pass2: last finishing block reduces and writes the scalar ----
    __threadfence();                     // order ws atomics before counter bump
    if (tid == 0) {
        unsigned old = atomicAdd((unsigned*)(ws + 2 * NBINS * nsets), 1u);
        isLast = (old == (unsigned)(gridDim.x - 1)) ? 1 : 0;
    }
    __syncthreads();
    if (isLast && tid < 64) {            // wave 0 of the last block = old pass2
        const int t = tid;
        float col = 0.0f;
        if (t < 2 * NBINS) {
            for (int s = 0; s < nsets; ++s)
                col += atomicAdd(&ws[s * 2 * NBINS + t], 0.0f);  // coherent read
        }
        float sse = col;
        float cnt = __shfl(col, t + 20);

        float w = 0.0f;
        if (t < NBINS) {
            float c = fmaxf(cnt, 1.0f);
            w = __powf(c, -0.9f);
        }
        float s2 = w;
        #pragma unroll
        for (int off = 32; off > 0; off >>= 1) s2 += __shfl_down(s2, off);
        s2 = __shfl(s2, 0);

        float wb = (s2 > 0.0f) ? (w * (20.0f / s2)) : w;
        wb = fmaxf(wb, 1.0f);

        float contrib = (t < NBINS) ? (wb * sse) : 0.0f;
        #pragma unroll
        for (int off = 32; off > 0; off >>= 1) contrib += __shfl_down(contrib, off);

        if (t == 0) out[0] = contrib * inv_n;
    }
}

extern "C" void kernel_launch(void* const* d_in, const int* in_sizes, int n_in,
                              void* d_out, int out_size, void* d_ws, size_t ws_size,
                              hipStream_t stream)
{
    const float* pred = (const float*)d_in[0];
    const float* targ = (const float*)d_in[1];
    float*       out  = (float*)d_out;
    float*       ws   = (float*)d_ws;
    const int n = in_sizes[0];

    int nsets = NSETS;
    while ((size_t)nsets * 2 * NBINS * sizeof(float) + sizeof(unsigned) > ws_size && nsets > 1)
        nsets >>= 1;

    // zero the partial slots AND the done-counter that sits right after them
    hipMemsetAsync(d_ws, 0, (size_t)nsets * 2 * NBINS * sizeof(float) + sizeof(unsigned), stream);
    dwmse_pass1<<<BLOCKS, TPB, 0, stream>>>(pred, targ, ws, out, n, nsets - 1, nsets,
                                            1.0f / (float)n);
}

// Round 9
// 181.894 us; speedup vs baseline: 2.2669x; 2.2669x over previous
//
#include <hip/hip_runtime.h>

#define NBINS   20
#define NSETS   32          // replicated count-accumulator sets (power of 2)
#define BLOCKS  2048
#define TPB     256

__device__ __forceinline__ int bin_of(float t)
{
    return min(max((int)(t * 20.0f), 0), NBINS - 1);   // same bin fn as all passing rounds
}

// ---------------- Pass A: exact bin counts via wave ballot ----------------
// Routing cost collapses from 45 VALU/elem to ~0.4: one v_cmp per bin per
// 64-lane column; popcount+add run on the SCALAR pipe; counts are
// wave-uniform (SGPR-resident). Memory: targ only (67 MB) -> ~11 us floor.
__global__ __launch_bounds__(TPB, 8)
void dwmse_count(const float* __restrict__ targ, float* __restrict__ ws,
                 int n, int setMask)
{
    __shared__ int hc[(TPB / 64) * NBINS];
    const int tid  = threadIdx.x;
    const int lane = tid & 63;
    const int wv   = tid >> 6;

    int cnt[NBINS];
    #pragma unroll
    for (int b = 0; b < NBINS; ++b) cnt[b] = 0;

    const int n4 = n >> 2;
    const float4* t4 = reinterpret_cast<const float4*>(targ);
    const int idx0    = blockIdx.x * TPB + tid;
    const int gstride = gridDim.x * TPB;
    const int iters   = n4 / gstride;         // uniform trip count (8 @ N=2^24)
    const int rem     = n4 - iters * gstride;

    const float4* tt = t4 + idx0;
    for (int it = 0; it < iters; ++it) {
        float4 t = tt[0];
        tt += gstride;
        int b0 = bin_of(t.x), b1 = bin_of(t.y), b2 = bin_of(t.z), b3 = bin_of(t.w);
        #pragma unroll
        for (int bb = 0; bb < NBINS; ++bb) {
            cnt[bb] += __popcll(__ballot(b0 == bb)) + __popcll(__ballot(b1 == bb))
                     + __popcll(__ballot(b2 == bb)) + __popcll(__ballot(b3 == bb));
        }
    }
    // remainder float4 tile (threads idx0 < rem), predicated via b = -1
    {
        int b0 = -1, b1 = -1, b2 = -1, b3 = -1;
        if (idx0 < rem) {
            float4 t = t4[iters * gstride + idx0];
            b0 = bin_of(t.x); b1 = bin_of(t.y); b2 = bin_of(t.z); b3 = bin_of(t.w);
        }
        #pragma unroll
        for (int bb = 0; bb < NBINS; ++bb) {
            cnt[bb] += __popcll(__ballot(b0 == bb)) + __popcll(__ballot(b1 == bb))
                     + __popcll(__ballot(b2 == bb)) + __popcll(__ballot(b3 == bb));
        }
    }
    // scalar tail (n % 4 elements; at most one per thread since gstride >= 4)
    {
        int b0 = -1;
        const int k = (n4 << 2) + idx0;
        if (k < n) b0 = bin_of(targ[k]);
        #pragma unroll
        for (int bb = 0; bb < NBINS; ++bb)
            cnt[bb] += __popcll(__ballot(b0 == bb));
    }

    // lane bb exports cnt[bb] (wave-uniform -> 20 cndmask once per wave)
    int myc = 0;
    #pragma unroll
    for (int bb = 0; bb < NBINS; ++bb) myc = (lane == bb) ? cnt[bb] : myc;
    if (lane < NBINS) hc[wv * NBINS + lane] = myc;
    __syncthreads();
    if (tid < NBINS) {
        int s = 0;
        #pragma unroll
        for (int w = 0; w < TPB / 64; ++w) s += hc[w * NBINS + tid];
        const int set = (int)(blockIdx.x) & setMask;
        unsafeAtomicAdd(&ws[set * NBINS + tid], (float)s);  // counts <= 2^24: exact in f32
    }
}

// ---------------- Pass C: weighted SSE in one stream ----------------
// Each block rebuilds the 20 weights from the finalized counts (visible
// across the dispatch boundary), stages them in LDS (banks 0..19 ->
// conflict-free broadcast reads), then streams pred+targ computing
// acc += w[bin(t)] * (p-t)^2 — the same per-element product the reference
// takes. ~7 VALU + 1 ds_read per element -> HBM-bound (~21 us @ 134 MB).
__global__ __launch_bounds__(TPB, 8)
void dwmse_wsse(const float* __restrict__ pred, const float* __restrict__ targ,
                const float* __restrict__ ws, float* __restrict__ out,
                int n, int nsets, float inv_n)
{
    __shared__ float wl[NBINS];
    __shared__ float hr[TPB / 64];
    const int tid = threadIdx.x;

    // ---- per-block weight build (wave 0), identical math to the old pass2 ----
    if (tid < 64) {
        const int t = tid;
        float cntv = 0.0f;
        if (t < NBINS) {
            for (int s = 0; s < nsets; ++s) cntv += ws[s * NBINS + t];
        }
        float w = 0.0f;
        if (t < NBINS) {
            float c = fmaxf(cntv, 1.0f);
            w = __powf(c, -0.9f);
        }
        float s2 = w;
        #pragma unroll
        for (int off = 32; off > 0; off >>= 1) s2 += __shfl_down(s2, off);
        s2 = __shfl(s2, 0);
        float wb = (s2 > 0.0f) ? (w * (20.0f / s2)) : w;
        wb = fmaxf(wb, 1.0f);
        if (t < NBINS) wl[t] = wb;
    }
    __syncthreads();

    float acc = 0.0f;

    const int n4 = n >> 2;
    const float4* p4 = reinterpret_cast<const float4*>(pred);
    const float4* t4 = reinterpret_cast<const float4*>(targ);
    const int idx0    = blockIdx.x * TPB + tid;
    const int gstride = gridDim.x * TPB;
    const int iters   = n4 / gstride;
    const int rem     = n4 - iters * gstride;

    const float4* pp = p4 + idx0;
    const float4* tt = t4 + idx0;
    for (int it = 0; it < iters; ++it) {
        float4 p = pp[0];
        float4 t = tt[0];
        pp += gstride; tt += gstride;
        float w0 = wl[bin_of(t.x)], w1 = wl[bin_of(t.y)];
        float w2 = wl[bin_of(t.z)], w3 = wl[bin_of(t.w)];
        float d0 = p.x - t.x, d1 = p.y - t.y, d2 = p.z - t.z, d3 = p.w - t.w;
        acc = fmaf(d0 * d0, w0, acc);
        acc = fmaf(d1 * d1, w1, acc);
        acc = fmaf(d2 * d2, w2, acc);
        acc = fmaf(d3 * d3, w3, acc);
    }
    if (idx0 < rem) {
        float4 p = p4[iters * gstride + idx0];
        float4 t = t4[iters * gstride + idx0];
        float w0 = wl[bin_of(t.x)], w1 = wl[bin_of(t.y)];
        float w2 = wl[bin_of(t.z)], w3 = wl[bin_of(t.w)];
        float d0 = p.x - t.x, d1 = p.y - t.y, d2 = p.z - t.z, d3 = p.w - t.w;
        acc = fmaf(d0 * d0, w0, acc);
        acc = fmaf(d1 * d1, w1, acc);
        acc = fmaf(d2 * d2, w2, acc);
        acc = fmaf(d3 * d3, w3, acc);
    }
    for (int k = (n4 << 2) + idx0; k < n; k += gstride) {
        float t = targ[k];
        float d = pred[k] - t;
        acc = fmaf(d * d, wl[bin_of(t)], acc);
    }

    // ---- block reduction -> one atomic into (zeroed) out ----
    #pragma unroll
    for (int off = 32; off > 0; off >>= 1) acc += __shfl_down(acc, off);
    if ((tid & 63) == 0) hr[tid >> 6] = acc;
    __syncthreads();
    if (tid == 0) {
        float blk = 0.0f;
        #pragma unroll
        for (int w = 0; w < TPB / 64; ++w) blk += hr[w];
        unsafeAtomicAdd(out, blk * inv_n);
    }
}

extern "C" void kernel_launch(void* const* d_in, const int* in_sizes, int n_in,
                              void* d_out, int out_size, void* d_ws, size_t ws_size,
                              hipStream_t stream)
{
    const float* pred = (const float*)d_in[0];
    const float* targ = (const float*)d_in[1];
    float*       out  = (float*)d_out;
    float*       ws   = (float*)d_ws;
    const int n = in_sizes[0];

    int nsets = NSETS;
    while ((size_t)nsets * NBINS * sizeof(float) > ws_size && nsets > 1) nsets >>= 1;

    hipMemsetAsync(d_ws, 0, (size_t)nsets * NBINS * sizeof(float), stream);
    hipMemsetAsync(d_out, 0, sizeof(float), stream);   // out accumulates atomically
    dwmse_count<<<BLOCKS, TPB, 0, stream>>>(targ, ws, n, nsets - 1);
    dwmse_wsse<<<BLOCKS, TPB, 0, stream>>>(pred, targ, ws, out, n, nsets,
                                           1.0f / (float)n);
}

// Round 10
// 181.524 us; speedup vs baseline: 2.2715x; 1.0020x over previous
//
#include <hip/hip_runtime.h>

#define NBINS   20
#define NSETS   32          // replicated count-accumulator sets (power of 2)
#define BLOCKS  2048
#define TPB     256

__device__ __forceinline__ int bin_of(float t)
{
    return min(max((int)(t * 20.0f), 0), NBINS - 1);   // same bin fn as all passing rounds
}

__device__ __forceinline__ void count_body(const float4 t, int (&cnt)[NBINS])
{
    int b0 = bin_of(t.x), b1 = bin_of(t.y), b2 = bin_of(t.z), b3 = bin_of(t.w);
    #pragma unroll
    for (int bb = 0; bb < NBINS; ++bb) {
        cnt[bb] += __popcll(__ballot(b0 == bb)) + __popcll(__ballot(b1 == bb))
                 + __popcll(__ballot(b2 == bb)) + __popcll(__ballot(b3 == bb));
    }
}

__device__ __forceinline__ float wsse_body(const float4 p, const float4 t,
                                           const float* __restrict__ wl, float acc)
{
    float w0 = wl[bin_of(t.x)], w1 = wl[bin_of(t.y)];
    float w2 = wl[bin_of(t.z)], w3 = wl[bin_of(t.w)];
    float d0 = p.x - t.x, d1 = p.y - t.y, d2 = p.z - t.z, d3 = p.w - t.w;
    acc = fmaf(d0 * d0, w0, acc);
    acc = fmaf(d1 * d1, w1, acc);
    acc = fmaf(d2 * d2, w2, acc);
    acc = fmaf(d3 * d3, w3, acc);
    return acc;
}

// ---------------- Pass A: exact bin counts via wave ballot ----------------
// r10: depth-2 branch-free pipeline (3 tiles in flight). cnt[20] + 3x float4
// + addresses ~= 45 regs, well under the (TPB,4)=128 cap -> the counted
// vmcnt pipeline survives register allocation (r5's failure was the 64-cap
// with acc[20] resident).
__global__ __launch_bounds__(TPB, 4)
void dwmse_count(const float* __restrict__ targ, float* __restrict__ ws,
                 int n, int setMask)
{
    __shared__ int hc[(TPB / 64) * NBINS];
    const int tid  = threadIdx.x;
    const int lane = tid & 63;
    const int wv   = tid >> 6;

    int cnt[NBINS];
    #pragma unroll
    for (int b = 0; b < NBINS; ++b) cnt[b] = 0;

    const int n4 = n >> 2;
    const float4* t4 = reinterpret_cast<const float4*>(targ);
    const int idx0    = blockIdx.x * TPB + tid;
    const int gstride = gridDim.x * TPB;
    const int iters   = n4 / gstride;         // uniform trip count (8 @ N=2^24)
    const int rem     = n4 - iters * gstride;

    if (iters >= 2) {
        const float4* tt = t4 + idx0;
        float4 ta = tt[0];
        float4 tb = tt[gstride];
        for (int it = 0; it < iters - 2; ++it) {
            float4 tc = tt[2 * gstride];          // unconditional 2-ahead load
            tt += gstride;
            count_body(ta, cnt);
            ta = tb; tb = tc;
        }
        count_body(ta, cnt);
        count_body(tb, cnt);
    } else if (iters == 1) {
        count_body(t4[idx0], cnt);
    }
    // remainder float4 tile (threads idx0 < rem), predicated via b = -1
    {
        int b0 = -1, b1 = -1, b2 = -1, b3 = -1;
        if (idx0 < rem) {
            float4 t = t4[iters * gstride + idx0];
            b0 = bin_of(t.x); b1 = bin_of(t.y); b2 = bin_of(t.z); b3 = bin_of(t.w);
        }
        #pragma unroll
        for (int bb = 0; bb < NBINS; ++bb) {
            cnt[bb] += __popcll(__ballot(b0 == bb)) + __popcll(__ballot(b1 == bb))
                     + __popcll(__ballot(b2 == bb)) + __popcll(__ballot(b3 == bb));
        }
    }
    // scalar tail (n % 4 elements; at most one per thread since gstride >= 4)
    {
        int b0 = -1;
        const int k = (n4 << 2) + idx0;
        if (k < n) b0 = bin_of(targ[k]);
        #pragma unroll
        for (int bb = 0; bb < NBINS; ++bb)
            cnt[bb] += __popcll(__ballot(b0 == bb));
    }

    // lane bb exports cnt[bb] (wave-uniform -> 20 cndmask once per wave)
    int myc = 0;
    #pragma unroll
    for (int bb = 0; bb < NBINS; ++bb) myc = (lane == bb) ? cnt[bb] : myc;
    if (lane < NBINS) hc[wv * NBINS + lane] = myc;
    __syncthreads();
    if (tid < NBINS) {
        int s = 0;
        #pragma unroll
        for (int w = 0; w < TPB / 64; ++w) s += hc[w * NBINS + tid];
        const int set = (int)(blockIdx.x) & setMask;
        unsafeAtomicAdd(&ws[set * NBINS + tid], (float)s);  // counts <= 2^24: exact in f32
    }
}

// ---------------- Pass C: weighted SSE in one stream ----------------
// r10: depth-2 branch-free pipeline. 3 tiles x (p,t) = 48 regs + ~16 base
// under the 128 cap -> 6 KB in flight per wave (vs 2 KB consumed-immediately
// in r9, which sat at 46.5 us / 2.9 TB/s delivered, VALU 8.7% = latency-bound).
__global__ __launch_bounds__(TPB, 4)
void dwmse_wsse(const float* __restrict__ pred, const float* __restrict__ targ,
                const float* __restrict__ ws, float* __restrict__ out,
                int n, int nsets, float inv_n)
{
    __shared__ float wl[NBINS];
    __shared__ float hr[TPB / 64];
    const int tid = threadIdx.x;

    // ---- per-block weight build (wave 0), identical math to the old pass2 ----
    if (tid < 64) {
        const int t = tid;
        float cntv = 0.0f;
        if (t < NBINS) {
            for (int s = 0; s < nsets; ++s) cntv += ws[s * NBINS + t];
        }
        float w = 0.0f;
        if (t < NBINS) {
            float c = fmaxf(cntv, 1.0f);
            w = __powf(c, -0.9f);
        }
        float s2 = w;
        #pragma unroll
        for (int off = 32; off > 0; off >>= 1) s2 += __shfl_down(s2, off);
        s2 = __shfl(s2, 0);
        float wb = (s2 > 0.0f) ? (w * (20.0f / s2)) : w;
        wb = fmaxf(wb, 1.0f);
        if (t < NBINS) wl[t] = wb;
    }
    __syncthreads();

    float acc = 0.0f;

    const int n4 = n >> 2;
    const float4* p4 = reinterpret_cast<const float4*>(pred);
    const float4* t4 = reinterpret_cast<const float4*>(targ);
    const int idx0    = blockIdx.x * TPB + tid;
    const int gstride = gridDim.x * TPB;
    const int iters   = n4 / gstride;
    const int rem     = n4 - iters * gstride;

    if (iters >= 2) {
        const float4* pp = p4 + idx0;
        const float4* tt = t4 + idx0;
        float4 pa = pp[0];       float4 ta = tt[0];
        float4 pb = pp[gstride]; float4 tb = tt[gstride];
        for (int it = 0; it < iters - 2; ++it) {
            float4 pc = pp[2 * gstride];          // unconditional 2-ahead loads
            float4 tc = tt[2 * gstride];
            pp += gstride; tt += gstride;
            acc = wsse_body(pa, ta, wl, acc);
            pa = pb; ta = tb;
            pb = pc; tb = tc;
        }
        acc = wsse_body(pa, ta, wl, acc);
        acc = wsse_body(pb, tb, wl, acc);
    } else if (iters == 1) {
        acc = wsse_body(p4[idx0], t4[idx0], wl, acc);
    }
    if (idx0 < rem) {
        acc = wsse_body(p4[iters * gstride + idx0], t4[iters * gstride + idx0], wl, acc);
    }
    for (int k = (n4 << 2) + idx0; k < n; k += gstride) {
        float t = targ[k];
        float d = pred[k] - t;
        acc = fmaf(d * d, wl[bin_of(t)], acc);
    }

    // ---- block reduction -> one atomic into (zeroed) out ----
    #pragma unroll
    for (int off = 32; off > 0; off >>= 1) acc += __shfl_down(acc, off);
    if ((tid & 63) == 0) hr[tid >> 6] = acc;
    __syncthreads();
    if (tid == 0) {
        float blk = 0.0f;
        #pragma unroll
        for (int w = 0; w < TPB / 64; ++w) blk += hr[w];
        unsafeAtomicAdd(out, blk * inv_n);
    }
}

extern "C" void kernel_launch(void* const* d_in, const int* in_sizes, int n_in,
                              void* d_out, int out_size, void* d_ws, size_t ws_size,
                              hipStream_t stream)
{
    const float* pred = (const float*)d_in[0];
    const float* targ = (const float*)d_in[1];
    float*       out  = (float*)d_out;
    float*       ws   = (float*)d_ws;
    const int n = in_sizes[0];

    int nsets = NSETS;
    while ((size_t)nsets * NBINS * sizeof(float) > ws_size && nsets > 1) nsets >>= 1;

    hipMemsetAsync(d_ws, 0, (size_t)nsets * NBINS * sizeof(float), stream);
    hipMemsetAsync(d_out, 0, sizeof(float), stream);   // out accumulates atomically
    dwmse_count<<<BLOCKS, TPB, 0, stream>>>(targ, ws, n, nsets - 1);
    dwmse_wsse<<<BLOCKS, TPB, 0, stream>>>(pred, targ, ws, out, n, nsets,
                                           1.0f / (float)n);
}